// Round 1
// baseline (108.309 us; speedup 1.0000x reference)
//
#include <hip/hip_runtime.h>
#include <math.h>

#define B 512
#define M 4096
#define T 48
#define BTILE 4          // b rows per block in distance kernel
#define MTILE 1024       // m values per block
#define NMT (M / MTILE)  // 4 m-tiles

// ws layout (element offsets in 4-byte units):
//   [0,    2048)  partial min value, float,  [b*NMT + mt]
//   [2048, 4096)  partial min index, int
//   [4096, 4608)  final argmin index, int, per b
//   [4608, 5120)  nll, float, per b

// ---------------- Kernel 1: tiled distance + per-tile argmin ----------------
__global__ __launch_bounds__(256) void k_dist(const float* __restrict__ target,
                                              const float* __restrict__ memory,
                                              float* __restrict__ pval,
                                              int* __restrict__ pidx) {
    const int tid = threadIdx.x;
    const int mt  = blockIdx.x;            // m-tile
    const int b0  = blockIdx.y * BTILE;    // first b of this block

    __shared__ float gt[BTILE * T * 2];    // 384 floats, broadcast-read
    for (int j = tid; j < BTILE * T * 2; j += 256)
        gt[j] = target[b0 * (T * 2) + j];  // target[:,0] is contiguous (B,T,2)
    __syncthreads();

    float bestv[BTILE];
    int   besti[BTILE];
#pragma unroll
    for (int i = 0; i < BTILE; ++i) { bestv[i] = INFINITY; besti[i] = 0x7fffffff; }

    for (int mi = 0; mi < MTILE / 256; ++mi) {
        const int m = mt * MTILE + mi * 256 + tid;
        const float4* mrow = (const float4*)(memory + (size_t)m * (T * 2)); // 24 float4 = 48 (x,y)
        float acc[BTILE] = {0.f, 0.f, 0.f, 0.f};
#pragma unroll
        for (int tq = 0; tq < T / 2; ++tq) {           // each float4 covers t=2q, 2q+1
            float4 mv = mrow[tq];
#pragma unroll
            for (int i = 0; i < BTILE; ++i) {
                float gx0 = gt[i * (T * 2) + tq * 4 + 0];
                float gy0 = gt[i * (T * 2) + tq * 4 + 1];
                float gx1 = gt[i * (T * 2) + tq * 4 + 2];
                float gy1 = gt[i * (T * 2) + tq * 4 + 3];
                float dx0 = mv.x - gx0, dy0 = mv.y - gy0;
                float dx1 = mv.z - gx1, dy1 = mv.w - gy1;
                acc[i] += sqrtf(dx0 * dx0 + dy0 * dy0);
                acc[i] += sqrtf(dx1 * dx1 + dy1 * dy1);
            }
        }
#pragma unroll
        for (int i = 0; i < BTILE; ++i) {
            // m strictly increases per thread, so strict < keeps lowest index
            if (acc[i] < bestv[i]) { bestv[i] = acc[i]; besti[i] = m; }
        }
    }

    // block tree-reduction (deterministic), one b at a time
    __shared__ float sv[256];
    __shared__ int   si[256];
    for (int i = 0; i < BTILE; ++i) {
        sv[tid] = bestv[i];
        si[tid] = besti[i];
        __syncthreads();
        for (int s = 128; s > 0; s >>= 1) {
            if (tid < s) {
                float v2 = sv[tid + s]; int i2 = si[tid + s];
                if (v2 < sv[tid] || (v2 == sv[tid] && i2 < si[tid])) {
                    sv[tid] = v2; si[tid] = i2;
                }
            }
            __syncthreads();
        }
        if (tid == 0) {
            pval[(b0 + i) * NMT + mt] = sv[0];
            pidx[(b0 + i) * NMT + mt] = si[0];
        }
        __syncthreads();
    }
}

// ---------------- Kernel 2: final argmin across m-tiles ----------------
__global__ void k_argmin_final(const float* __restrict__ pval,
                               const int* __restrict__ pidx,
                               int* __restrict__ idx_out,
                               float* __restrict__ idx_f_out) {
    int b = blockIdx.x * blockDim.x + threadIdx.x;
    if (b >= B) return;
    float bv = INFINITY; int bi = 0x7fffffff;
    for (int mt = 0; mt < NMT; ++mt) {     // ascending tiles → lowest index on ties
        float v = pval[b * NMT + mt];
        int   i = pidx[b * NMT + mt];
        if (v < bv || (v == bv && i < bi)) { bv = v; bi = i; }
    }
    idx_out[b]   = bi;
    idx_f_out[b] = (float)bi;
}

// ---------------- Kernel 3: per-row LSE + NLL gather ----------------
__global__ __launch_bounds__(256) void k_nll(const float* __restrict__ preds,
                                             const int* __restrict__ idx,
                                             float* __restrict__ nll) {
    const int b = blockIdx.x;
    const int tid = threadIdx.x;
    const float4* row = (const float4*)(preds + (size_t)b * M);  // 1024 float4

    float4 v[4];
    float mx = -INFINITY;
#pragma unroll
    for (int j = 0; j < 4; ++j) {
        v[j] = row[tid + j * 256];
        mx = fmaxf(mx, fmaxf(fmaxf(v[j].x, v[j].y), fmaxf(v[j].z, v[j].w)));
    }

    __shared__ float red[256];
    red[tid] = mx; __syncthreads();
    for (int s = 128; s > 0; s >>= 1) {
        if (tid < s) red[tid] = fmaxf(red[tid], red[tid + s]);
        __syncthreads();
    }
    mx = red[0];
    __syncthreads();

    float sum = 0.f;
#pragma unroll
    for (int j = 0; j < 4; ++j)
        sum += expf(v[j].x - mx) + expf(v[j].y - mx) + expf(v[j].z - mx) + expf(v[j].w - mx);

    red[tid] = sum; __syncthreads();
    for (int s = 128; s > 0; s >>= 1) {
        if (tid < s) red[tid] += red[tid + s];
        __syncthreads();
    }
    if (tid == 0) {
        float lse = mx + logf(red[0]);
        nll[b] = lse - preds[(size_t)b * M + idx[b]];   // -(x[i] - lse)
    }
}

// ---------------- Kernel 4: mean over B ----------------
__global__ __launch_bounds__(512) void k_mean(const float* __restrict__ nll,
                                              float* __restrict__ out) {
    __shared__ float red[512];
    int tid = threadIdx.x;
    red[tid] = nll[tid]; __syncthreads();
    for (int s = 256; s > 0; s >>= 1) {
        if (tid < s) red[tid] += red[tid + s];
        __syncthreads();
    }
    if (tid == 0) out[0] = red[0] * (1.0f / B);
}

extern "C" void kernel_launch(void* const* d_in, const int* in_sizes, int n_in,
                              void* d_out, int out_size, void* d_ws, size_t ws_size,
                              hipStream_t stream) {
    const float* preds  = (const float*)d_in[0];  // (512, 4096)
    const float* target = (const float*)d_in[1];  // (512, 1, 48, 2)
    const float* memory = (const float*)d_in[2];  // (4096, 48, 2)
    float* out = (float*)d_out;                   // [loss, idx[512]]

    char* ws = (char*)d_ws;
    float* pval = (float*)ws;                  // 2048 floats
    int*   pidx = (int*)(ws + 2048 * 4);       // 2048 ints
    int*   idx  = (int*)(ws + 4096 * 4);       // 512 ints
    float* nll  = (float*)(ws + 4608 * 4);     // 512 floats

    dim3 g1(NMT, B / BTILE);                   // 4 x 128 = 512 blocks
    k_dist<<<g1, 256, 0, stream>>>(target, memory, pval, pidx);
    k_argmin_final<<<2, 256, 0, stream>>>(pval, pidx, idx, out + 1);
    k_nll<<<B, 256, 0, stream>>>(preds, idx, nll);
    k_mean<<<1, 512, 0, stream>>>(nll, out);
}

// Round 2
// 39.740 us; speedup vs baseline: 2.7254x; 2.7254x over previous
//
#include <hip/hip_runtime.h>
#include <math.h>

#define B 512
#define M 4096
#define T 48
#define MCHUNK 16
#define NCH (M / MCHUNK)   // 256 m-chunks

// ws layout (bytes):
//   [0,    4096)  best[b]: packed (float_bits(dist)<<32 | m), u64, per b
//   [4096, 6144)  nll, float, per b

// ---------------- Kernel 0: init packed-min slots ----------------
__global__ void k_init(unsigned long long* best) {
    best[threadIdx.x] = 0xFFFFFFFFFFFFFFFFULL;
}

// ---------------- Kernel 1: lane-per-b distance + packed atomicMin ----------
// lane = one batch row b (target row held in 96 registers);
// memory row address is wave-uniform -> scalar loads.
__global__ __launch_bounds__(256, 2) void k_dist(const float* __restrict__ target,
                                                 const float* __restrict__ memory,
                                                 unsigned long long* __restrict__ best) {
    const int b  = blockIdx.y * 256 + threadIdx.x;
    const int m0 = blockIdx.x * MCHUNK;

    // Per-lane target row -> registers (static indices only)
    float gt[T * 2];
    const float4* tg = (const float4*)(target + (size_t)b * (T * 2));
#pragma unroll
    for (int q = 0; q < T / 2; ++q) {
        float4 v = tg[q];
        gt[4 * q + 0] = v.x; gt[4 * q + 1] = v.y;
        gt[4 * q + 2] = v.z; gt[4 * q + 3] = v.w;
    }

    float bestv = INFINITY;
    int   besti = 0;

    for (int mi = 0; mi < MCHUNK; ++mi) {
        const int m = m0 + mi;                       // wave-uniform
        const float4* mr = (const float4*)(memory + (size_t)m * (T * 2));
        float a0 = 0.f, a1 = 0.f, a2 = 0.f, a3 = 0.f;
#pragma unroll
        for (int q = 0; q < T / 2; ++q) {
            float4 mv = mr[q];                       // uniform addr -> s_load
            float dx0 = mv.x - gt[4 * q + 0];
            float dy0 = mv.y - gt[4 * q + 1];
            float dx1 = mv.z - gt[4 * q + 2];
            float dy1 = mv.w - gt[4 * q + 3];
            float s0 = __builtin_amdgcn_sqrtf(fmaf(dx0, dx0, dy0 * dy0));
            float s1 = __builtin_amdgcn_sqrtf(fmaf(dx1, dx1, dy1 * dy1));
            if (q & 1) { a2 += s0; a3 += s1; }
            else       { a0 += s0; a1 += s1; }
        }
        float d = (a0 + a2) + (a1 + a3);
        if (d < bestv) { bestv = d; besti = m; }     // ascending m -> lowest idx on tie
    }

    // positive float bits compare like uint; low word = index -> lowest index wins ties
    unsigned long long pack =
        ((unsigned long long)__float_as_uint(bestv) << 32) | (unsigned int)besti;
    atomicMin(&best[b], pack);
}

// ---------------- Kernel 2: per-row LSE + NLL gather (+ index output) -------
__global__ __launch_bounds__(256) void k_nll(const float* __restrict__ preds,
                                             const unsigned long long* __restrict__ best,
                                             float* __restrict__ nll,
                                             float* __restrict__ idx_f_out) {
    const int b   = blockIdx.x;
    const int tid = threadIdx.x;
    const int idx = (int)(unsigned int)(best[b] & 0xFFFFFFFFULL);
    const float4* row = (const float4*)(preds + (size_t)b * M);  // 1024 float4

    float4 v[4];
    float mx = -INFINITY;
#pragma unroll
    for (int j = 0; j < 4; ++j) {
        v[j] = row[tid + j * 256];
        mx = fmaxf(mx, fmaxf(fmaxf(v[j].x, v[j].y), fmaxf(v[j].z, v[j].w)));
    }

    __shared__ float red[256];
    red[tid] = mx; __syncthreads();
    for (int s = 128; s > 0; s >>= 1) {
        if (tid < s) red[tid] = fmaxf(red[tid], red[tid + s]);
        __syncthreads();
    }
    mx = red[0];
    __syncthreads();

    float sum = 0.f;
#pragma unroll
    for (int j = 0; j < 4; ++j)
        sum += expf(v[j].x - mx) + expf(v[j].y - mx) + expf(v[j].z - mx) + expf(v[j].w - mx);

    red[tid] = sum; __syncthreads();
    for (int s = 128; s > 0; s >>= 1) {
        if (tid < s) red[tid] += red[tid + s];
        __syncthreads();
    }
    if (tid == 0) {
        float lse = mx + logf(red[0]);
        nll[b] = lse - preds[(size_t)b * M + idx];
        idx_f_out[b] = (float)idx;
    }
}

// ---------------- Kernel 3: mean over B ----------------
__global__ __launch_bounds__(512) void k_mean(const float* __restrict__ nll,
                                              float* __restrict__ out) {
    __shared__ float red[512];
    int tid = threadIdx.x;
    red[tid] = nll[tid]; __syncthreads();
    for (int s = 256; s > 0; s >>= 1) {
        if (tid < s) red[tid] += red[tid + s];
        __syncthreads();
    }
    if (tid == 0) out[0] = red[0] * (1.0f / B);
}

extern "C" void kernel_launch(void* const* d_in, const int* in_sizes, int n_in,
                              void* d_out, int out_size, void* d_ws, size_t ws_size,
                              hipStream_t stream) {
    const float* preds  = (const float*)d_in[0];  // (512, 4096)
    const float* target = (const float*)d_in[1];  // (512, 1, 48, 2)
    const float* memory = (const float*)d_in[2];  // (4096, 48, 2)
    float* out = (float*)d_out;                   // [loss, idx[512]]

    char* ws = (char*)d_ws;
    unsigned long long* best = (unsigned long long*)ws;  // 512 u64
    float* nll = (float*)(ws + 4096);                    // 512 floats

    k_init<<<1, B, 0, stream>>>(best);
    dim3 g1(NCH, B / 256);                               // 256 x 2 = 512 blocks
    k_dist<<<g1, 256, 0, stream>>>(target, memory, best);
    k_nll<<<B, 256, 0, stream>>>(preds, best, nll, out + 1);
    k_mean<<<1, 512, 0, stream>>>(nll, out);
}